// Round 10
// baseline (123.572 us; speedup 1.0000x reference)
//
#include <hip/hip_runtime.h>

// out[t,c] = bias[c] + sum_{k=0..99} w_norm[k,c] * x[t+k-99, c]   (x zero-padded t<0)
// T=16384, NC=2048, FW=100, all float32.
//
// R10: two kernels.
//  1) prep_w: per-channel relu + L2-normalize + transpose into static device
//     buffer g_wT[2048][104] (w'[0]=0, w'[1..100]=relu*scl, w'[101..103]=0).
//  2) catent_fir: x in channel-major LDS ring (ds_read_b128, stride 292,
//     conflict-free per R4); weights as 26 float4 VMEM loads/chunk with static
//     offsets (L1/L2-hot), double-buffered at distance 2. This removes the
//     ~500 non-FMA VALU/chunk (addr arith + fmaxf) that R9's counters showed
//     were ~30% of all cycles.
//  Register policy: __launch_bounds__(256,2) (only proven no-spill pin).
//  Grid: NSEG=8 -> 512 blocks = 2/CU balanced.

#define T_TOT 16384
#define NCH   2048
#define FW    100
#define CB    32          // channels per block
#define TB    128         // time steps per chunk
#define NTHR  256
#define ROWL  292         // ring row stride (floats): 256 + 36 pad (mirror [0,32)->[256,288))
#define WTL   104         // wT row length
#define NSEG  8           // 64 cgroups * 8 = 512 blocks = exactly 2/CU
#define NCHUNK (T_TOT / TB / NSEG)   // 16 chunks per segment

__device__ float g_wT[NCH * WTL];   // 852 KB, rewritten by prep_w every launch

__global__ void prep_w(const float* __restrict__ wraw) {
    int c = blockIdx.x * 256 + threadIdx.x;   // 0..2047
    const float* wcol = wraw + c;
    float s = 0.0f;
    for (int k = 0; k < FW; ++k) {
        float v = fmaxf(wcol[(size_t)k * NCH], 0.0f);
        s = fmaf(v, v, s);
    }
    float scl = rsqrtf(fmaxf(s, 1e-12f));
    float* wr = g_wT + (size_t)c * WTL;
    wr[0] = 0.0f;
    for (int j = 1; j <= FW; ++j)
        wr[j] = fmaxf(wcol[(size_t)(j - 1) * NCH], 0.0f) * scl;
    wr[101] = 0.0f; wr[102] = 0.0f; wr[103] = 0.0f;
}

// Step KI (=1..12): taps j=KI*8..KI*8+7 from wk buffer pair (WB0,WB1), loads
// 8 new x into xw[NS..NS+7], 128 FMAs at phase PH, then (if DOLD) refills the
// just-consumed weight buffer with taps at wrow[LDOFF..LDOFF+7] (distance-2).
#define KC_STEP(KI, PH, NS, WB0, WB1, DOLD, LDOFF) do {                         \
    int ro_ = (base0 + (KI)*8 + 16) & 255;                                      \
    float4 n0_ = *(const float4*)(rrow + ro_);                                  \
    float4 n1_ = *(const float4*)(rrow + ro_ + 4);                              \
    float wk_[8];                                                               \
    wk_[0]=WB0.x; wk_[1]=WB0.y; wk_[2]=WB0.z; wk_[3]=WB0.w;                     \
    wk_[4]=WB1.x; wk_[5]=WB1.y; wk_[6]=WB1.z; wk_[7]=WB1.w;                     \
    if (DOLD) {                                                                 \
        WB0 = *(const float4*)(wrow + (LDOFF));                                 \
        WB1 = *(const float4*)(wrow + (LDOFF) + 4);                             \
    }                                                                           \
    xw[(NS)+0]=n0_.x; xw[(NS)+1]=n0_.y; xw[(NS)+2]=n0_.z; xw[(NS)+3]=n0_.w;     \
    xw[(NS)+4]=n1_.x; xw[(NS)+5]=n1_.y; xw[(NS)+6]=n1_.z; xw[(NS)+7]=n1_.w;     \
    _Pragma("unroll")                                                           \
    for (int u_ = 0; u_ < 8; ++u_) {                                            \
      _Pragma("unroll")                                                         \
      for (int i_ = 0; i_ < 16; ++i_)                                           \
        acc[i_] = fmaf(wk_[u_], xw[((PH) + u_ + i_) % 24], acc[i_]);            \
    }                                                                           \
} while (0)

__global__ __launch_bounds__(NTHR, 2)
void catent_fir(const float* __restrict__ x,
                const float* __restrict__ bias,
                float* __restrict__ out) {
    __shared__ __align__(16) float ring[CB * ROWL];   // 37376 B

    const int tid   = threadIdx.x;
    const int cgrp  = blockIdx.x & 63;
    const int sidx  = blockIdx.x >> 6;          // 0..NSEG-1
    const int cbase = cgrp * CB;

    const int ch0 = sidx * NCHUNK;
    const int tseg0 = ch0 * TB;

    const int c = tid & 31;
    const int g = tid >> 5;              // 0..7

    // ---- prologue: stage times [tseg0-128, tseg0+127]; mirror [0,32)->[256,288) ----
    {
        float* rw = &ring[c * ROWL];
        for (int p = 0; p < 2; ++p) {
            int tbase = tseg0 - TB + p * TB + g * 16;
            float v[16];
            #pragma unroll
            for (int j = 0; j < 16; ++j) {
                int t = tbase + j;
                v[j] = (t >= 0) ? x[(size_t)t * NCH + cbase + c] : 0.0f;
            }
            int rm = tbase & 255;
            #pragma unroll
            for (int q = 0; q < 4; ++q)
                *(float4*)(rw + rm + q * 4) = make_float4(v[q*4], v[q*4+1], v[q*4+2], v[q*4+3]);
            if (rm < 32) {
                #pragma unroll
                for (int q = 0; q < 4; ++q)
                    *(float4*)(rw + 256 + rm + q * 4) = make_float4(v[q*4], v[q*4+1], v[q*4+2], v[q*4+3]);
            }
        }
    }
    __syncthreads();

    const float biasr = bias[cbase + c];
    const float* rrow = &ring[c * ROWL];
    const float* wrow = g_wT + (size_t)(cbase + c) * WTL;
    float* rwr = &ring[c * ROWL];

    for (int ch = ch0; ch < ch0 + NCHUNK; ++ch) {
        const int t0 = ch * TB;
        const bool do_stage = (ch + 1 < ch0 + NCHUNK);

        // weight double-buffer preload: steps 0 and 1
        float4 wA0 = *(const float4*)(wrow);
        float4 wA1 = *(const float4*)(wrow + 4);
        float4 wB0 = *(const float4*)(wrow + 8);
        float4 wB1 = *(const float4*)(wrow + 12);

        float acc[16];
        #pragma unroll
        for (int i = 0; i < 16; ++i) acc[i] = biasr;

        float xw[24];
        const int base0 = t0 + g * 16 - 100;     // multiple of 4 -> 16B-aligned ring reads

        // step 0: fill xw[0..23] = x[base0..base0+23]; taps 0..7 (w'[0]=0 in wT);
        // then reload wA <- taps 16..23 (for step 2)
        {
            int ro = base0 & 255;
            #pragma unroll
            for (int q = 0; q < 6; ++q) {
                float4 v = *(const float4*)(rrow + ro + q * 4);
                xw[q*4+0] = v.x; xw[q*4+1] = v.y; xw[q*4+2] = v.z; xw[q*4+3] = v.w;
            }
            float wk[8];
            wk[0]=wA0.x; wk[1]=wA0.y; wk[2]=wA0.z; wk[3]=wA0.w;
            wk[4]=wA1.x; wk[5]=wA1.y; wk[6]=wA1.z; wk[7]=wA1.w;
            wA0 = *(const float4*)(wrow + 16);
            wA1 = *(const float4*)(wrow + 20);
            #pragma unroll
            for (int u = 0; u < 8; ++u) {
                #pragma unroll
                for (int i = 0; i < 16; ++i)
                    acc[i] = fmaf(wk[u], xw[(u + i) % 24], acc[i]);
            }
        }

        // steps 1..12: slide window by 8; weight buffers alternate B,A,B,... dist-2
        KC_STEP(1,  8,  0, wB0, wB1, 1, 24);
        KC_STEP(2, 16,  8, wA0, wA1, 1, 32);
        KC_STEP(3,  0, 16, wB0, wB1, 1, 40);
        KC_STEP(4,  8,  0, wA0, wA1, 1, 48);
        KC_STEP(5, 16,  8, wB0, wB1, 1, 56);
        KC_STEP(6,  0, 16, wA0, wA1, 1, 64);
        KC_STEP(7,  8,  0, wB0, wB1, 1, 72);
        KC_STEP(8, 16,  8, wA0, wA1, 1, 80);
        KC_STEP(9,  0, 16, wB0, wB1, 1, 88);
        KC_STEP(10, 8,  0, wA0, wA1, 1, 96);
        KC_STEP(11,16,  8, wB0, wB1, 0, 0);
        KC_STEP(12, 0, 16, wA0, wA1, 0, 0);

        __syncthreads();   // all ring reads of this chunk done

        if (do_stage) {    // stage next chunk: global -> regs -> LDS (between barriers)
            const int tb = t0 + TB + g * 16;
            const size_t gb = (size_t)tb * NCH + cbase + c;
            float sv[16];
            #pragma unroll
            for (int j = 0; j < 16; ++j) sv[j] = x[gb + (size_t)j * NCH];
            int rm = tb & 255;
            #pragma unroll
            for (int q = 0; q < 4; ++q)
                *(float4*)(rwr + rm + q * 4) = make_float4(sv[q*4], sv[q*4+1], sv[q*4+2], sv[q*4+3]);
            if (rm < 32) {
                #pragma unroll
                for (int q = 0; q < 4; ++q)
                    *(float4*)(rwr + 256 + rm + q * 4) = make_float4(sv[q*4], sv[q*4+1], sv[q*4+2], sv[q*4+3]);
            }
        }
        __syncthreads();   // staged rows visible for next chunk

        // stores drain under next chunk's compute
        {
            size_t ob = (size_t)(t0 + g * 16) * NCH + cbase + c;
            #pragma unroll
            for (int i = 0; i < 16; ++i) out[ob + (size_t)i * NCH] = acc[i];
        }
    }
}

extern "C" void kernel_launch(void* const* d_in, const int* in_sizes, int n_in,
                              void* d_out, int out_size, void* d_ws, size_t ws_size,
                              hipStream_t stream) {
    const float* x    = (const float*)d_in[0];   // [T, NC]
    const float* wraw = (const float*)d_in[1];   // [FW, NC]
    const float* bias = (const float*)d_in[2];   // [1, NC]
    float* out = (float*)d_out;                  // [T, NC]

    prep_w<<<dim3(NCH / 256), dim3(256), 0, stream>>>(wraw);
    catent_fir<<<dim3(64 * NSEG), dim3(NTHR), 0, stream>>>(x, bias, out);
}